// Round 6
// baseline (1277.477 us; speedup 1.0000x reference)
//
#include <hip/hip_runtime.h>
#include <cstddef>

typedef _Float16 f16x8 __attribute__((ext_vector_type(8)));
typedef float f32x4 __attribute__((ext_vector_type(4)));

// Problem constants
constexpr int BATCH = 128;
constexpr int T     = 16;
constexpr int ROWS  = BATCH * T * T;  // 32768
constexpr int WID   = 100;
constexpr int NB    = 50;
constexpr int KP    = 128;            // padded K (4 MFMA k-steps of 32)
constexpr int NP    = 128;            // padded N (8 col-tiles of 16)
constexpr int RPW   = 64;             // rows per workgroup
constexpr int WCH   = 16384;          // f16 elements per fragment-imaged matrix

// ---------------------------------------------------------------------------
// Prep: split weights into f16 hi/lo pairs (w = hi + lo, lo = w - (f16)w) in
// MFMA B-fragment stream order. Chunk (bk,m,kap,tau) is 1KB: lane L, elem i ->
// W[k=32*kap+(L>>4)*8+i][col=16*tau+(L&15)], zero-padded outside 100x100.
// Also colsum of Wa for the b1 scalar-bias fold.
// ---------------------------------------------------------------------------
__global__ __launch_bounds__(256) void prep_kernel(
    const float* __restrict__ Wa, const float* __restrict__ Wb,
    _Float16* __restrict__ whi, _Float16* __restrict__ wlo,
    float* __restrict__ csA) {
  const int bid = blockIdx.x;          // 0..99 = bk*2 + m
  const int bk = bid >> 1, m = bid & 1;
  const float* src = (m ? Wb : Wa) + (size_t)bk * (WID * WID);
  _Float16* dh = whi + (size_t)bid * WCH;
  _Float16* dl = wlo + (size_t)bid * WCH;
  for (int e = threadIdx.x; e < WCH; e += 256) {
    const int i   = e & 7;
    const int L   = (e >> 3) & 63;
    const int tau = (e >> 9) & 7;
    const int kap = e >> 12;
    const int k   = 32 * kap + (L >> 4) * 8 + i;
    const int col = 16 * tau + (L & 15);
    const float v = (k < WID && col < WID) ? src[k * WID + col] : 0.0f;
    const _Float16 hi = (_Float16)v;
    dh[e] = hi;
    dl[e] = (_Float16)(v - (float)hi);
  }
  if (!m) {
    for (int col = threadIdx.x; col < NP; col += 256) {
      float s = 0.0f;
      if (col < WID) {
        for (int k = 0; k < WID; ++k) s += src[k * WID + col];
      }
      csA[bk * NP + col] = s;
    }
  }
}

// ---------------------------------------------------------------------------
// First layer: gather 45-wide stencil rows, x0 = relu(flat @ W0)
// ---------------------------------------------------------------------------
__global__ __launch_bounds__(256) void first_layer_kernel(
    const float* __restrict__ inp, const float* __restrict__ W0,
    float* __restrict__ x0) {
  __shared__ float w0s[45 * WID];
  for (int i = threadIdx.x; i < 45 * WID; i += 256) w0s[i] = W0[i];
  __syncthreads();

  const int rq  = threadIdx.x >> 2;
  const int cq  = threadIdx.x & 3;
  const int row = blockIdx.x * 64 + rq;
  const int b   = row >> 8;
  const int t1  = (row >> 4) & 15;
  const int t2  = row & 15;
  const int g1  = 2 * t1, g2 = 2 * t2;
  const int g1m = (g1 + 31) & 31, g2m = (g2 + 31) & 31;
  const float* base = inp + (size_t)b * (32 * 32 * 9);
  const float* p0 = base + ((g1 + 1) * 32 + g2) * 9;
  const float* p1 = base + (g1m * 32 + g2) * 9;
  const float* p2 = base + (g1 * 32 + (g2 + 1)) * 9;
  const float* p3 = base + (g1 * 32 + g2m) * 9;
  const float* p4 = base + (g1 * 32 + g2) * 9;

  float f[45];
#pragma unroll
  for (int qq = 0; qq < 9; ++qq) {
    f[qq]      = p0[qq];
    f[9 + qq]  = p1[qq];
    f[18 + qq] = p2[qq];
    f[27 + qq] = p3[qq];
    f[36 + qq] = p4[qq];
  }

  float acc[25];
#pragma unroll
  for (int j = 0; j < 25; ++j) acc[j] = 0.0f;
  const int j0 = cq * 25;
#pragma unroll
  for (int k = 0; k < 45; ++k) {
    const float fv = f[k];
#pragma unroll
    for (int j = 0; j < 25; ++j) acc[j] += fv * w0s[k * WID + j0 + j];
  }
  float* orow = x0 + (size_t)row * WID + j0;
#pragma unroll
  for (int j = 0; j < 25; ++j) orow[j] = fmaxf(acc[j], 0.0f);
}

// ---------------------------------------------------------------------------
// Chain: 50 residual blocks, split-f16 MFMA (f32 accum, error ~2^-22).
// 512 WGs x 256 thr. LDS: x hi/lo only, f16 [64][128] XOR-swizzled
// (k ^ ((row&7)<<3)); v overwrites x IN PLACE (fp32 residual x in registers),
// 4 barriers/block -> LDS 32 KB -> 4 WG/CU (4 waves/SIMD TLP).
// Weights read global->VGPR directly (per-wave-owned fragment chunks).
// Per GEMM per wave: 16 B-loads(global), 32 A-reads(ds b128), 96 MFMA.
// ---------------------------------------------------------------------------
__global__ __launch_bounds__(256, 4) void chain_kernel(
    float* __restrict__ x0,
    const _Float16* __restrict__ whi, const _Float16* __restrict__ wlo,
    const float* __restrict__ csA,
    const float* __restrict__ B1, const float* __restrict__ B2,
    const float* __restrict__ B3, const float* __restrict__ B4,
    const float* __restrict__ M) {
  __shared__ __align__(16) _Float16 xhs[RPW * KP];   // 16 KB
  __shared__ __align__(16) _Float16 xls[RPW * KP];   // 16 KB

  const int tid  = threadIdx.x;
  const int lane = tid & 63;
  const int uw   = __builtin_amdgcn_readfirstlane(tid >> 6);  // wave 0..3
  const int q    = lane >> 4;   // 0..3
  const int fr   = lane & 15;   // 0..15
  const int rbase = blockIdx.x * RPW;

  // fill x hi/lo (f32 -> split f16, swizzled)
  for (int i = tid; i < RPW * KP; i += 256) {
    const int row = i >> 7, k = i & 127;
    const float v = (k < WID) ? x0[(size_t)(rbase + row) * WID + k] : 0.0f;
    const _Float16 hi = (_Float16)v;
    const int a = row * KP + (k ^ ((row & 7) << 3));
    xhs[a] = hi;
    xls[a] = (_Float16)(v - (float)hi);
  }

  // fp32 residual state: 4 row-tiles x 2 col-tiles x 4 regs
  int colc[2];
#pragma unroll
  for (int c = 0; c < 2; ++c) colc[c] = 16 * (2 * uw + c) + fr;
  float xres[4][2][4];
#pragma unroll
  for (int rt = 0; rt < 4; ++rt)
#pragma unroll
    for (int c = 0; c < 2; ++c)
#pragma unroll
      for (int rg = 0; rg < 4; ++rg) {
        const int row = 16 * rt + 4 * q + rg;
        xres[rt][c][rg] = (colc[c] < WID)
            ? x0[(size_t)(rbase + row) * WID + colc[c]] : 0.0f;
      }
  __syncthreads();

  f32x4 acc[4][2];
  auto zero_acc = [&]() {
#pragma unroll
    for (int rt = 0; rt < 4; ++rt)
#pragma unroll
      for (int c = 0; c < 2; ++c) acc[rt][c] = (f32x4){0.f, 0.f, 0.f, 0.f};
  };

  // split-f16 GEMM: acc += (ah+al) @ (bh+bl), dropping al*bl (~2^-22)
  auto kloop = [&](const _Float16* __restrict__ gh,
                   const _Float16* __restrict__ gl) {
    f16x8 bh[4][2], bl[4][2];
#pragma unroll
    for (int kap = 0; kap < 4; ++kap)
#pragma unroll
      for (int c = 0; c < 2; ++c) {
        const int off = (kap * 8 + 2 * uw + c) * 512 + lane * 8;
        bh[kap][c] = *(const f16x8*)&gh[off];
        bl[kap][c] = *(const f16x8*)&gl[off];
      }
#pragma unroll
    for (int kap = 0; kap < 4; ++kap) {
      f16x8 ah[4], al[4];
#pragma unroll
      for (int rt = 0; rt < 4; ++rt) {
        const int row = 16 * rt + fr;
        const int off = row * KP + ((32 * kap + 8 * q) ^ ((fr & 7) << 3));
        ah[rt] = *(const f16x8*)&xhs[off];
        al[rt] = *(const f16x8*)&xls[off];
      }
#pragma unroll
      for (int rt = 0; rt < 4; ++rt)
#pragma unroll
        for (int c = 0; c < 2; ++c) {
          acc[rt][c] = __builtin_amdgcn_mfma_f32_16x16x32_f16(
              ah[rt], bh[kap][c], acc[rt][c], 0, 0, 0);
          acc[rt][c] = __builtin_amdgcn_mfma_f32_16x16x32_f16(
              ah[rt], bl[kap][c], acc[rt][c], 0, 0, 0);
          acc[rt][c] = __builtin_amdgcn_mfma_f32_16x16x32_f16(
              al[rt], bh[kap][c], acc[rt][c], 0, 0, 0);
        }
    }
  };

  for (int bk = 0; bk < NB; ++bk) {
    // ---------------- GEMM1: v = 2*relu(2*((x+b1)@Wa) + b2) + b3 ----------
    zero_acc();
    kloop(whi + (size_t)(bk * 2) * WCH, wlo + (size_t)(bk * 2) * WCH);
    __syncthreads();            // all x reads done; xs reusable
    {
      const float b1 = B1[bk], b2 = B2[bk], b3 = B3[bk];
      const float csv[2] = {csA[bk * NP + colc[0]], csA[bk * NP + colc[1]]};
#pragma unroll
      for (int rt = 0; rt < 4; ++rt)
#pragma unroll
        for (int c = 0; c < 2; ++c)
#pragma unroll
          for (int rg = 0; rg < 4; ++rg) {
            const int row = 16 * rt + 4 * q + rg;
            const float t = 2.0f * (acc[rt][c][rg] + b1 * csv[c]) + b2;
            const float v = 2.0f * fmaxf(t, 0.0f) + b3;
            const _Float16 hi = (_Float16)v;
            const int a = row * KP + (colc[c] ^ ((row & 7) << 3));
            xhs[a] = hi;
            xls[a] = (_Float16)(v - (float)hi);
          }
    }
    __syncthreads();            // publish v

    // ---------------- GEMM2: x = relu(x + (v@Wb)*m + b4) -------------------
    zero_acc();
    kloop(whi + (size_t)(bk * 2 + 1) * WCH, wlo + (size_t)(bk * 2 + 1) * WCH);
    __syncthreads();            // all v reads done; xs reusable
    {
      const float b4v = B4[bk], mm = M[bk];
#pragma unroll
      for (int rt = 0; rt < 4; ++rt)
#pragma unroll
        for (int c = 0; c < 2; ++c)
#pragma unroll
          for (int rg = 0; rg < 4; ++rg) {
            const int row = 16 * rt + 4 * q + rg;
            const float xn = fmaxf(xres[rt][c][rg] + acc[rt][c][rg] * mm + b4v, 0.0f);
            xres[rt][c][rg] = xn;
            const _Float16 hi = (_Float16)xn;
            const int a = row * KP + (colc[c] ^ ((row & 7) << 3));
            xhs[a] = hi;
            xls[a] = (_Float16)(xn - (float)hi);
          }
    }
    __syncthreads();            // publish x(bk+1)
  }

  // write back fp32 residual state
#pragma unroll
  for (int rt = 0; rt < 4; ++rt)
#pragma unroll
    for (int c = 0; c < 2; ++c)
#pragma unroll
      for (int rg = 0; rg < 4; ++rg) {
        const int row = 16 * rt + 4 * q + rg;
        if (colc[c] < WID)
          x0[(size_t)(rbase + row) * WID + colc[c]] = xres[rt][c][rg];
      }
}

// ---------------------------------------------------------------------------
// Output head + stencil epilogue. One block per batch image (16x16 grid).
// ---------------------------------------------------------------------------
__global__ __launch_bounds__(256) void out_kernel(
    const float* __restrict__ inp, const float* __restrict__ x0,
    const float* __restrict__ Wout, const float* __restrict__ bout,
    float* __restrict__ out) {
  __shared__ float ys[256 * 4];
  __shared__ float wouts[WID * 4];
  __shared__ float bos[4];
  const int tid = threadIdx.x;
  const int b   = blockIdx.x;

  for (int i = tid; i < WID * 4; i += 256) wouts[i] = Wout[i];
  if (tid < 4) bos[tid] = bout[tid];
  __syncthreads();

  const int row = b * 256 + tid;
  const float* xr = x0 + (size_t)row * WID;
  float a0 = 0.f, a1 = 0.f, a2 = 0.f, a3 = 0.f;
#pragma unroll 4
  for (int k = 0; k < WID; ++k) {
    const float xv = xr[k];
    a0 += xv * wouts[k * 4 + 0];
    a1 += xv * wouts[k * 4 + 1];
    a2 += xv * wouts[k * 4 + 2];
    a3 += xv * wouts[k * 4 + 3];
  }
  ys[tid * 4 + 0] = a0 + bos[0];
  ys[tid * 4 + 1] = a1 + bos[1];
  ys[tid * 4 + 2] = a2 + bos[2];
  ys[tid * 4 + 3] = a3 + bos[3];
  __syncthreads();

  const int i = tid >> 4, j = tid & 15;
  const int ip1 = (i + 1) & 15, im1 = (i + 15) & 15;
  const int jp1 = (j + 1) & 15, jm1 = (j + 15) & 15;
  auto Y = [&](int a, int c, int comp) { return ys[(((a << 4) | c) << 2) + comp]; };
  const float y0 = Y(i, j, 0), y1 = Y(i, j, 1), y2 = Y(i, j, 2), y3 = Y(i, j, 3);
  const float right_c = y0 / (Y(ip1, j, 1) + y0);
  const float left_c  = y1 / (y1 + Y(im1, j, 0));
  const float up_c    = y2 / (y2 + Y(i, jp1, 3));
  const float down_c  = y3 / (Y(i, jm1, 2) + y3);

  const float* base = inp + (size_t)b * (32 * 32 * 9);
  const int g1 = 2 * i + 1, g1m = (2 * i + 31) & 31;
  const int g2 = 2 * j + 1, g2m = (2 * j + 31) & 31;
  const float* oo = base + (g1 * 32 + g2) * 9;
  const float* oi = base + (g1 * 32 + g2m) * 9;
  const float* io = base + (g1m * 32 + g2) * 9;
  const float* ii = base + (g1m * 32 + g2m) * 9;
  const float ru = -(oo[0] + oo[3] * right_c + oo[1] * up_c) / oo[4];
  const float rd = -(oi[2] + oi[5] * right_c + oi[1] * down_c) / oi[4];
  const float lu = -(io[6] + io[3] * left_c + io[7] * up_c) / io[4];
  const float ld = -(ii[8] + ii[5] * left_c + ii[7] * down_c) / ii[4];

  float* o = out + (size_t)row * 9;
  o[0] = ld;     o[1] = left_c;  o[2] = lu;
  o[3] = down_c; o[4] = 1.0f;    o[5] = up_c;
  o[6] = rd;     o[7] = right_c; o[8] = ru;
}

// ---------------------------------------------------------------------------
extern "C" void kernel_launch(void* const* d_in, const int* in_sizes, int n_in,
                              void* d_out, int out_size, void* d_ws, size_t ws_size,
                              hipStream_t stream) {
  const float* inp  = (const float*)d_in[0];
  const float* W0   = (const float*)d_in[1];
  const float* Wa   = (const float*)d_in[2];
  const float* Wb   = (const float*)d_in[3];
  const float* B1   = (const float*)d_in[4];
  const float* B2   = (const float*)d_in[5];
  const float* B3   = (const float*)d_in[6];
  const float* B4   = (const float*)d_in[7];
  const float* M    = (const float*)d_in[8];
  const float* Wout = (const float*)d_in[9];
  const float* bout = (const float*)d_in[10];
  float* out = (float*)d_out;

  float* ws       = (float*)d_ws;
  float* x0       = ws;                            // 3,276,800 f32
  _Float16* whi   = (_Float16*)(ws + 3276800);     // 100*16384 f16 (819,200 f32)
  _Float16* wlo   = (_Float16*)(ws + 3276800 + 819200);
  float* csA      = ws + 3276800 + 819200 + 819200; // 50*128 f32

  hipLaunchKernelGGL(prep_kernel, dim3(100), dim3(256), 0, stream,
                     Wa, Wb, whi, wlo, csA);
  hipLaunchKernelGGL(first_layer_kernel, dim3(ROWS / 64), dim3(256), 0, stream,
                     inp, W0, x0);
  hipLaunchKernelGGL(chain_kernel, dim3(ROWS / RPW), dim3(256), 0, stream,
                     x0, whi, wlo, csA, B1, B2, B3, B4, M);
  hipLaunchKernelGGL(out_kernel, dim3(BATCH), dim3(256), 0, stream,
                     inp, x0, Wout, bout, out);
}

// Round 7
// 380.868 us; speedup vs baseline: 3.3541x; 3.3541x over previous
//
#include <hip/hip_runtime.h>
#include <cstddef>

typedef _Float16 f16x8 __attribute__((ext_vector_type(8)));
typedef float f32x4 __attribute__((ext_vector_type(4)));

// Problem constants
constexpr int BATCH = 128;
constexpr int T     = 16;
constexpr int ROWS  = BATCH * T * T;  // 32768
constexpr int WID   = 100;
constexpr int NB    = 50;
constexpr int KP    = 128;            // padded K (4 MFMA k-steps of 32)
constexpr int NP    = 128;            // padded N (8 col-tiles of 16)
constexpr int RPW   = 64;             // rows per workgroup
constexpr int WCH   = 16384;          // f16 elements per fragment-imaged matrix

// ---------------------------------------------------------------------------
// Prep: split weights into f16 hi/lo pairs (w = hi + lo, lo = w - (f16)w) in
// MFMA B-fragment stream order. Chunk (bk,m,kap,tau) is 1KB: lane L, elem i ->
// W[k=32*kap+(L>>4)*8+i][col=16*tau+(L&15)], zero-padded outside 100x100.
// Also colsum of Wa for the b1 scalar-bias fold.
// ---------------------------------------------------------------------------
__global__ __launch_bounds__(256) void prep_kernel(
    const float* __restrict__ Wa, const float* __restrict__ Wb,
    _Float16* __restrict__ whi, _Float16* __restrict__ wlo,
    float* __restrict__ csA) {
  const int bid = blockIdx.x;          // 0..99 = bk*2 + m
  const int bk = bid >> 1, m = bid & 1;
  const float* src = (m ? Wb : Wa) + (size_t)bk * (WID * WID);
  _Float16* dh = whi + (size_t)bid * WCH;
  _Float16* dl = wlo + (size_t)bid * WCH;
  for (int e = threadIdx.x; e < WCH; e += 256) {
    const int i   = e & 7;
    const int L   = (e >> 3) & 63;
    const int tau = (e >> 9) & 7;
    const int kap = e >> 12;
    const int k   = 32 * kap + (L >> 4) * 8 + i;
    const int col = 16 * tau + (L & 15);
    const float v = (k < WID && col < WID) ? src[k * WID + col] : 0.0f;
    const _Float16 hi = (_Float16)v;
    dh[e] = hi;
    dl[e] = (_Float16)(v - (float)hi);
  }
  if (!m) {
    for (int col = threadIdx.x; col < NP; col += 256) {
      float s = 0.0f;
      if (col < WID) {
        for (int k = 0; k < WID; ++k) s += src[k * WID + col];
      }
      csA[bk * NP + col] = s;
    }
  }
}

// ---------------------------------------------------------------------------
// First layer: gather 45-wide stencil rows, x0 = relu(flat @ W0)
// ---------------------------------------------------------------------------
__global__ __launch_bounds__(256) void first_layer_kernel(
    const float* __restrict__ inp, const float* __restrict__ W0,
    float* __restrict__ x0) {
  __shared__ float w0s[45 * WID];
  for (int i = threadIdx.x; i < 45 * WID; i += 256) w0s[i] = W0[i];
  __syncthreads();

  const int rq  = threadIdx.x >> 2;
  const int cq  = threadIdx.x & 3;
  const int row = blockIdx.x * 64 + rq;
  const int b   = row >> 8;
  const int t1  = (row >> 4) & 15;
  const int t2  = row & 15;
  const int g1  = 2 * t1, g2 = 2 * t2;
  const int g1m = (g1 + 31) & 31, g2m = (g2 + 31) & 31;
  const float* base = inp + (size_t)b * (32 * 32 * 9);
  const float* p0 = base + ((g1 + 1) * 32 + g2) * 9;
  const float* p1 = base + (g1m * 32 + g2) * 9;
  const float* p2 = base + (g1 * 32 + (g2 + 1)) * 9;
  const float* p3 = base + (g1 * 32 + g2m) * 9;
  const float* p4 = base + (g1 * 32 + g2) * 9;

  float f[45];
#pragma unroll
  for (int qq = 0; qq < 9; ++qq) {
    f[qq]      = p0[qq];
    f[9 + qq]  = p1[qq];
    f[18 + qq] = p2[qq];
    f[27 + qq] = p3[qq];
    f[36 + qq] = p4[qq];
  }

  float acc[25];
#pragma unroll
  for (int j = 0; j < 25; ++j) acc[j] = 0.0f;
  const int j0 = cq * 25;
#pragma unroll
  for (int k = 0; k < 45; ++k) {
    const float fv = f[k];
#pragma unroll
    for (int j = 0; j < 25; ++j) acc[j] += fv * w0s[k * WID + j0 + j];
  }
  float* orow = x0 + (size_t)row * WID + j0;
#pragma unroll
  for (int j = 0; j < 25; ++j) orow[j] = fmaxf(acc[j], 0.0f);
}

// ---------------------------------------------------------------------------
// Chain: 50 residual blocks, split-f16 MFMA (f32 accum, error ~2^-22).
// 512 WGs x 256 thr. LDS: x hi/lo only, f16 [64][128] XOR-swizzled
// (k ^ ((row&7)<<3)); v overwrites x IN PLACE (fp32 residual x in registers).
// LDS 32 KB; launch_bounds (256,2) -> compiler picks 128 VGPR (no spill,
// proven R5); occupancy VGPR-bound at 4 WG/CU.
// Weights read global->VGPR directly (per-wave-owned fragment chunks).
// Per GEMM per wave: 16 B-loads(global), 32 A-reads(ds b128), 96 MFMA.
// ---------------------------------------------------------------------------
__global__ __launch_bounds__(256, 2) void chain_kernel(
    float* __restrict__ x0,
    const _Float16* __restrict__ whi, const _Float16* __restrict__ wlo,
    const float* __restrict__ csA,
    const float* __restrict__ B1, const float* __restrict__ B2,
    const float* __restrict__ B3, const float* __restrict__ B4,
    const float* __restrict__ M) {
  __shared__ __align__(16) _Float16 xhs[RPW * KP];   // 16 KB
  __shared__ __align__(16) _Float16 xls[RPW * KP];   // 16 KB

  const int tid  = threadIdx.x;
  const int lane = tid & 63;
  const int uw   = __builtin_amdgcn_readfirstlane(tid >> 6);  // wave 0..3
  const int q    = lane >> 4;   // 0..3
  const int fr   = lane & 15;   // 0..15
  const int rbase = blockIdx.x * RPW;

  // fill x hi/lo (f32 -> split f16, swizzled)
  for (int i = tid; i < RPW * KP; i += 256) {
    const int row = i >> 7, k = i & 127;
    const float v = (k < WID) ? x0[(size_t)(rbase + row) * WID + k] : 0.0f;
    const _Float16 hi = (_Float16)v;
    const int a = row * KP + (k ^ ((row & 7) << 3));
    xhs[a] = hi;
    xls[a] = (_Float16)(v - (float)hi);
  }

  // fp32 residual state: 4 row-tiles x 2 col-tiles x 4 regs
  int colc[2];
#pragma unroll
  for (int c = 0; c < 2; ++c) colc[c] = 16 * (2 * uw + c) + fr;
  float xres[4][2][4];
#pragma unroll
  for (int rt = 0; rt < 4; ++rt)
#pragma unroll
    for (int c = 0; c < 2; ++c)
#pragma unroll
      for (int rg = 0; rg < 4; ++rg) {
        const int row = 16 * rt + 4 * q + rg;
        xres[rt][c][rg] = (colc[c] < WID)
            ? x0[(size_t)(rbase + row) * WID + colc[c]] : 0.0f;
      }
  __syncthreads();

  f32x4 acc[4][2];
  auto zero_acc = [&]() {
#pragma unroll
    for (int rt = 0; rt < 4; ++rt)
#pragma unroll
      for (int c = 0; c < 2; ++c) acc[rt][c] = (f32x4){0.f, 0.f, 0.f, 0.f};
  };

  // split-f16 GEMM: acc += (ah+al) @ (bh+bl), dropping al*bl (~2^-22)
  auto kloop = [&](const _Float16* __restrict__ gh,
                   const _Float16* __restrict__ gl) {
    f16x8 bh[4][2], bl[4][2];
#pragma unroll
    for (int kap = 0; kap < 4; ++kap)
#pragma unroll
      for (int c = 0; c < 2; ++c) {
        const int off = (kap * 8 + 2 * uw + c) * 512 + lane * 8;
        bh[kap][c] = *(const f16x8*)&gh[off];
        bl[kap][c] = *(const f16x8*)&gl[off];
      }
#pragma unroll
    for (int kap = 0; kap < 4; ++kap) {
      f16x8 ah[4], al[4];
#pragma unroll
      for (int rt = 0; rt < 4; ++rt) {
        const int row = 16 * rt + fr;
        const int off = row * KP + ((32 * kap + 8 * q) ^ ((fr & 7) << 3));
        ah[rt] = *(const f16x8*)&xhs[off];
        al[rt] = *(const f16x8*)&xls[off];
      }
#pragma unroll
      for (int rt = 0; rt < 4; ++rt)
#pragma unroll
        for (int c = 0; c < 2; ++c) {
          acc[rt][c] = __builtin_amdgcn_mfma_f32_16x16x32_f16(
              ah[rt], bh[kap][c], acc[rt][c], 0, 0, 0);
          acc[rt][c] = __builtin_amdgcn_mfma_f32_16x16x32_f16(
              ah[rt], bl[kap][c], acc[rt][c], 0, 0, 0);
          acc[rt][c] = __builtin_amdgcn_mfma_f32_16x16x32_f16(
              al[rt], bh[kap][c], acc[rt][c], 0, 0, 0);
        }
    }
  };

  for (int bk = 0; bk < NB; ++bk) {
    // ---------------- GEMM1: v = 2*relu(2*((x+b1)@Wa) + b2) + b3 ----------
    zero_acc();
    kloop(whi + (size_t)(bk * 2) * WCH, wlo + (size_t)(bk * 2) * WCH);
    __syncthreads();            // all x reads done; xs reusable
    {
      const float b1 = B1[bk], b2 = B2[bk], b3 = B3[bk];
      const float csv[2] = {csA[bk * NP + colc[0]], csA[bk * NP + colc[1]]};
#pragma unroll
      for (int rt = 0; rt < 4; ++rt)
#pragma unroll
        for (int c = 0; c < 2; ++c)
#pragma unroll
          for (int rg = 0; rg < 4; ++rg) {
            const int row = 16 * rt + 4 * q + rg;
            const float t = 2.0f * (acc[rt][c][rg] + b1 * csv[c]) + b2;
            const float v = 2.0f * fmaxf(t, 0.0f) + b3;
            const _Float16 hi = (_Float16)v;
            const int a = row * KP + (colc[c] ^ ((row & 7) << 3));
            xhs[a] = hi;
            xls[a] = (_Float16)(v - (float)hi);
          }
    }
    __syncthreads();            // publish v

    // ---------------- GEMM2: x = relu(x + (v@Wb)*m + b4) -------------------
    zero_acc();
    kloop(whi + (size_t)(bk * 2 + 1) * WCH, wlo + (size_t)(bk * 2 + 1) * WCH);
    __syncthreads();            // all v reads done; xs reusable
    {
      const float b4v = B4[bk], mm = M[bk];
#pragma unroll
      for (int rt = 0; rt < 4; ++rt)
#pragma unroll
        for (int c = 0; c < 2; ++c)
#pragma unroll
          for (int rg = 0; rg < 4; ++rg) {
            const int row = 16 * rt + 4 * q + rg;
            const float xn = fmaxf(xres[rt][c][rg] + acc[rt][c][rg] * mm + b4v, 0.0f);
            xres[rt][c][rg] = xn;
            const _Float16 hi = (_Float16)xn;
            const int a = row * KP + (colc[c] ^ ((row & 7) << 3));
            xhs[a] = hi;
            xls[a] = (_Float16)(xn - (float)hi);
          }
    }
    __syncthreads();            // publish x(bk+1)
  }

  // write back fp32 residual state
#pragma unroll
  for (int rt = 0; rt < 4; ++rt)
#pragma unroll
    for (int c = 0; c < 2; ++c)
#pragma unroll
      for (int rg = 0; rg < 4; ++rg) {
        const int row = 16 * rt + 4 * q + rg;
        if (colc[c] < WID)
          x0[(size_t)(rbase + row) * WID + colc[c]] = xres[rt][c][rg];
      }
}

// ---------------------------------------------------------------------------
// Output head + stencil epilogue. One block per batch image (16x16 grid).
// ---------------------------------------------------------------------------
__global__ __launch_bounds__(256) void out_kernel(
    const float* __restrict__ inp, const float* __restrict__ x0,
    const float* __restrict__ Wout, const float* __restrict__ bout,
    float* __restrict__ out) {
  __shared__ float ys[256 * 4];
  __shared__ float wouts[WID * 4];
  __shared__ float bos[4];
  const int tid = threadIdx.x;
  const int b   = blockIdx.x;

  for (int i = tid; i < WID * 4; i += 256) wouts[i] = Wout[i];
  if (tid < 4) bos[tid] = bout[tid];
  __syncthreads();

  const int row = b * 256 + tid;
  const float* xr = x0 + (size_t)row * WID;
  float a0 = 0.f, a1 = 0.f, a2 = 0.f, a3 = 0.f;
#pragma unroll 4
  for (int k = 0; k < WID; ++k) {
    const float xv = xr[k];
    a0 += xv * wouts[k * 4 + 0];
    a1 += xv * wouts[k * 4 + 1];
    a2 += xv * wouts[k * 4 + 2];
    a3 += xv * wouts[k * 4 + 3];
  }
  ys[tid * 4 + 0] = a0 + bos[0];
  ys[tid * 4 + 1] = a1 + bos[1];
  ys[tid * 4 + 2] = a2 + bos[2];
  ys[tid * 4 + 3] = a3 + bos[3];
  __syncthreads();

  const int i = tid >> 4, j = tid & 15;
  const int ip1 = (i + 1) & 15, im1 = (i + 15) & 15;
  const int jp1 = (j + 1) & 15, jm1 = (j + 15) & 15;
  auto Y = [&](int a, int c, int comp) { return ys[(((a << 4) | c) << 2) + comp]; };
  const float y0 = Y(i, j, 0), y1 = Y(i, j, 1), y2 = Y(i, j, 2), y3 = Y(i, j, 3);
  const float right_c = y0 / (Y(ip1, j, 1) + y0);
  const float left_c  = y1 / (y1 + Y(im1, j, 0));
  const float up_c    = y2 / (y2 + Y(i, jp1, 3));
  const float down_c  = y3 / (Y(i, jm1, 2) + y3);

  const float* base = inp + (size_t)b * (32 * 32 * 9);
  const int g1 = 2 * i + 1, g1m = (2 * i + 31) & 31;
  const int g2 = 2 * j + 1, g2m = (2 * j + 31) & 31;
  const float* oo = base + (g1 * 32 + g2) * 9;
  const float* oi = base + (g1 * 32 + g2m) * 9;
  const float* io = base + (g1m * 32 + g2) * 9;
  const float* ii = base + (g1m * 32 + g2m) * 9;
  const float ru = -(oo[0] + oo[3] * right_c + oo[1] * up_c) / oo[4];
  const float rd = -(oi[2] + oi[5] * right_c + oi[1] * down_c) / oi[4];
  const float lu = -(io[6] + io[3] * left_c + io[7] * up_c) / io[4];
  const float ld = -(ii[8] + ii[5] * left_c + ii[7] * down_c) / ii[4];

  float* o = out + (size_t)row * 9;
  o[0] = ld;     o[1] = left_c;  o[2] = lu;
  o[3] = down_c; o[4] = 1.0f;    o[5] = up_c;
  o[6] = rd;     o[7] = right_c; o[8] = ru;
}

// ---------------------------------------------------------------------------
extern "C" void kernel_launch(void* const* d_in, const int* in_sizes, int n_in,
                              void* d_out, int out_size, void* d_ws, size_t ws_size,
                              hipStream_t stream) {
  const float* inp  = (const float*)d_in[0];
  const float* W0   = (const float*)d_in[1];
  const float* Wa   = (const float*)d_in[2];
  const float* Wb   = (const float*)d_in[3];
  const float* B1   = (const float*)d_in[4];
  const float* B2   = (const float*)d_in[5];
  const float* B3   = (const float*)d_in[6];
  const float* B4   = (const float*)d_in[7];
  const float* M    = (const float*)d_in[8];
  const float* Wout = (const float*)d_in[9];
  const float* bout = (const float*)d_in[10];
  float* out = (float*)d_out;

  float* ws       = (float*)d_ws;
  float* x0       = ws;                            // 3,276,800 f32
  _Float16* whi   = (_Float16*)(ws + 3276800);     // 100*16384 f16 (819,200 f32)
  _Float16* wlo   = (_Float16*)(ws + 3276800 + 819200);
  float* csA      = ws + 3276800 + 819200 + 819200; // 50*128 f32

  hipLaunchKernelGGL(prep_kernel, dim3(100), dim3(256), 0, stream,
                     Wa, Wb, whi, wlo, csA);
  hipLaunchKernelGGL(first_layer_kernel, dim3(ROWS / 64), dim3(256), 0, stream,
                     inp, W0, x0);
  hipLaunchKernelGGL(chain_kernel, dim3(ROWS / RPW), dim3(256), 0, stream,
                     x0, whi, wlo, csA, B1, B2, B3, B4, M);
  hipLaunchKernelGGL(out_kernel, dim3(BATCH), dim3(256), 0, stream,
                     inp, x0, Wout, bout, out);
}